// Round 1
// baseline (1160.103 us; speedup 1.0000x reference)
//
#include <hip/hip_runtime.h>
#include <hip/hip_bf16.h>

// Problem constants (reference: T,B,D,H = 1024,512,128,128)
#define T_STEPS 1024
#define BATCH   512
#define DIM     128
#define G3      384   // 3*H gate rows

typedef __attribute__((ext_vector_type(8))) short bf16x8;
typedef __attribute__((ext_vector_type(4))) float f32x4;

__device__ __forceinline__ short f2bf(float f) {
  unsigned u = __builtin_bit_cast(unsigned, f);
  u += 0x7FFFu + ((u >> 16) & 1u);   // round-to-nearest-even
  return (short)(u >> 16);
}

// ---------------------------------------------------------------------------
// Prep: Wc = W_ih @ W1 (bf16), W_hh -> bf16, bc = W_ih @ b1 + b_ih (fp32).
// grid 384 (one gate row g), block 128 (one output col d).
// ---------------------------------------------------------------------------
__global__ void prep_kernel(const float* __restrict__ W1, const float* __restrict__ b1,
                            const float* __restrict__ W_ih, const float* __restrict__ W_hh,
                            const float* __restrict__ b_ih,
                            short* __restrict__ wc_bf, short* __restrict__ whh_bf,
                            float* __restrict__ bc) {
  const int g = blockIdx.x;
  const int d = threadIdx.x;
  float acc = 0.f;
  #pragma unroll 4
  for (int k = 0; k < 128; ++k)
    acc = fmaf(W_ih[g * 128 + k], W1[k * 128 + d], acc);
  wc_bf[g * 128 + d]  = f2bf(acc);
  whh_bf[g * 128 + d] = f2bf(W_hh[g * 128 + d]);

  __shared__ float red[128];
  red[d] = W_ih[g * 128 + d] * b1[d];
  __syncthreads();
  #pragma unroll
  for (int s = 64; s > 0; s >>= 1) {
    if (d < s) red[d] += red[d + s];
    __syncthreads();
  }
  if (d == 0) bc[g] = red[0] + b_ih[g];
}

// ---------------------------------------------------------------------------
// Main GRU kernel. 256 blocks (2 batch chains each) x 256 threads (4 waves).
// Wave w owns gate slice [w*96, w*96+96): 6 N-tiles of 16, K = 128 = 4 tiles.
// Both weight matrices are held in registers as MFMA B-fragments (bf16).
// gi (input projection) is batched 8 timesteps at a time into one M=16 matmul;
// gh (recurrent) is one M=16 (2 live rows) matmul per step.
// mfma_f32_16x16x32_bf16 layouts (m89-verified):
//   A[m=lane&15][k=quad*8+j], B[k=quad*8+j][n=lane&15], D: col=lane&15,row=quad*4+reg
// ---------------------------------------------------------------------------
__global__ __launch_bounds__(256) void gru_kernel(
    const float* __restrict__ x,       // [T][B][D]
    const float* __restrict__ b_hh,    // [384]
    const short* __restrict__ wc_bf,   // [384][128] bf16
    const short* __restrict__ whh_bf,  // [384][128] bf16
    const float* __restrict__ bc,      // [384]
    float* __restrict__ out)           // [B][H]
{
  const int tid  = threadIdx.x;
  const int w    = tid >> 6;      // wave 0..3
  const int l    = tid & 63;
  const int quad = l >> 4;
  const int col  = l & 15;
  const int b0   = blockIdx.x * 2;

  __shared__ float gi_lds[16][385];   // [m = 2*trel+bsel][gate], padded (+1 breaks 4-way)
  __shared__ float gh_lds[2][384];
  __shared__ float h_f32[2][128];
  __shared__ short h_b16[2][128];
  __shared__ float bias_c[384];
  __shared__ float bias_h[384];

  // ---- load B-fragments (both weight matrices) into registers
  bf16x8 Bc[6][4], Bh[6][4];
  #pragma unroll
  for (int nt = 0; nt < 6; ++nt) {
    const int n = w * 96 + nt * 16 + col;
    #pragma unroll
    for (int kt = 0; kt < 4; ++kt) {
      const int off = n * 128 + kt * 32 + quad * 8;
      Bc[nt][kt] = *(const bf16x8*)(wc_bf + off);
      Bh[nt][kt] = *(const bf16x8*)(whh_bf + off);
    }
  }
  for (int i = tid; i < 384; i += 256) { bias_c[i] = bc[i]; bias_h[i] = b_hh[i]; }
  {
    const int bsel = tid >> 7, j = tid & 127;
    h_f32[bsel][j] = 0.f;
    h_b16[bsel][j] = 0;
  }
  __syncthreads();

  const f32x4 zero4 = {0.f, 0.f, 0.f, 0.f};

  for (int t0 = 0; t0 < T_STEPS; t0 += 8) {
    // ---- gi chunk: M=16 rows = (trel = m>>1, bsel = m&1) over 8 timesteps
    {
      bf16x8 Ax[4];
      const int trel = col >> 1, bsel = col & 1;
      const float* xp = x + ((size_t)(t0 + trel) * BATCH + (b0 + bsel)) * DIM + quad * 8;
      #pragma unroll
      for (int kt = 0; kt < 4; ++kt) {
        f32x4 v0 = *(const f32x4*)(xp + kt * 32);
        f32x4 v1 = *(const f32x4*)(xp + kt * 32 + 4);
        bf16x8 a;
        a[0] = f2bf(v0[0]); a[1] = f2bf(v0[1]); a[2] = f2bf(v0[2]); a[3] = f2bf(v0[3]);
        a[4] = f2bf(v1[0]); a[5] = f2bf(v1[1]); a[6] = f2bf(v1[2]); a[7] = f2bf(v1[3]);
        Ax[kt] = a;
      }
      f32x4 acc[6];
      #pragma unroll
      for (int nt = 0; nt < 6; ++nt) acc[nt] = zero4;
      #pragma unroll
      for (int kt = 0; kt < 4; ++kt)
        #pragma unroll
        for (int nt = 0; nt < 6; ++nt)
          acc[nt] = __builtin_amdgcn_mfma_f32_16x16x32_bf16(Ax[kt], Bc[nt][kt], acc[nt], 0, 0, 0);
      #pragma unroll
      for (int nt = 0; nt < 6; ++nt) {
        const int n = w * 96 + nt * 16 + col;
        #pragma unroll
        for (int r = 0; r < 4; ++r)
          gi_lds[quad * 4 + r][n] = acc[nt][r];
      }
    }
    __syncthreads();

    // ---- 8 recurrent steps
    #pragma unroll 1
    for (int s = 0; s < 8; ++s) {
      // h A-fragment: rows 0,1 real; rows >=2 duplicate row (col&1) -> outputs unused
      bf16x8 Ah[4];
      #pragma unroll
      for (int kt = 0; kt < 4; ++kt)
        Ah[kt] = *(const bf16x8*)(&h_b16[col & 1][kt * 32 + quad * 8]);

      f32x4 acc[6];
      #pragma unroll
      for (int nt = 0; nt < 6; ++nt) acc[nt] = zero4;
      #pragma unroll
      for (int kt = 0; kt < 4; ++kt)
        #pragma unroll
        for (int nt = 0; nt < 6; ++nt)
          acc[nt] = __builtin_amdgcn_mfma_f32_16x16x32_bf16(Ah[kt], Bh[nt][kt], acc[nt], 0, 0, 0);

      if (quad == 0) {   // rows 0,1 live in quad 0, regs 0,1
        #pragma unroll
        for (int nt = 0; nt < 6; ++nt) {
          const int n = w * 96 + nt * 16 + col;
          gh_lds[0][n] = acc[nt][0];
          gh_lds[1][n] = acc[nt][1];
        }
      }
      __syncthreads();

      // ---- gate math: 256 threads = 2 rows x 128 hidden units
      {
        const int bsel = tid >> 7, j = tid & 127;
        const int m = 2 * s + bsel;
        const float gir = gi_lds[m][j];
        const float giz = gi_lds[m][j + 128];
        const float gin = gi_lds[m][j + 256];
        const float ar = gir + bias_c[j]       + gh_lds[bsel][j]       + bias_h[j];
        const float az = giz + bias_c[j + 128] + gh_lds[bsel][j + 128] + bias_h[j + 128];
        const float hn_pre = gh_lds[bsel][j + 256] + bias_h[j + 256];
        const float r = 1.f / (1.f + __expf(-ar));
        const float z = 1.f / (1.f + __expf(-az));
        float nv = gin + bias_c[j + 256] + r * hn_pre;
        nv = fminf(fmaxf(nv, -15.f), 15.f);
        const float e = __expf(2.f * nv);
        const float n_t = (e - 1.f) / (e + 1.f);
        const float h_new = (1.f - z) * n_t + z * h_f32[bsel][j];
        h_f32[bsel][j] = h_new;
        h_b16[bsel][j] = f2bf(h_new);
      }
      __syncthreads();
    }
  }

  // ---- epilogue: final h -> out
  {
    const int bsel = tid >> 7, j = tid & 127;
    out[(size_t)(b0 + bsel) * DIM + j] = h_f32[bsel][j];
  }
}

// ---------------------------------------------------------------------------
extern "C" void kernel_launch(void* const* d_in, const int* in_sizes, int n_in,
                              void* d_out, int out_size, void* d_ws, size_t ws_size,
                              hipStream_t stream) {
  const float* x    = (const float*)d_in[0];
  const float* W1   = (const float*)d_in[1];
  const float* b1   = (const float*)d_in[2];
  const float* W_ih = (const float*)d_in[3];
  const float* W_hh = (const float*)d_in[4];
  const float* b_ih = (const float*)d_in[5];
  const float* b_hh = (const float*)d_in[6];
  float* out = (float*)d_out;

  char* ws = (char*)d_ws;
  short* wc_bf  = (short*)(ws);             // 384*128 bf16 = 98304 B
  short* whh_bf = (short*)(ws + 98304);     // 384*128 bf16 = 98304 B
  float* bc     = (float*)(ws + 196608);    // 384 fp32

  prep_kernel<<<dim3(G3), dim3(128), 0, stream>>>(W1, b1, W_ih, W_hh, b_ih, wc_bf, whh_bf, bc);
  gru_kernel<<<dim3(BATCH / 2), dim3(256), 0, stream>>>(x, b_hh, wc_bf, whh_bf, bc, out);
}

// Round 2
// 893.870 us; speedup vs baseline: 1.2978x; 1.2978x over previous
//
#include <hip/hip_runtime.h>
#include <hip/hip_bf16.h>

// Problem constants (reference: T,B,D,H = 1024,512,128,128)
#define T_STEPS 1024
#define BATCH   512
#define DIM     128
#define G3      384   // 3*H gate rows

typedef __attribute__((ext_vector_type(8))) short bf16x8;
typedef __attribute__((ext_vector_type(4))) float f32x4;

__device__ __forceinline__ short f2bf(float f) {
  unsigned u = __builtin_bit_cast(unsigned, f);
  u += 0x7FFFu + ((u >> 16) & 1u);   // round-to-nearest-even
  return (short)(u >> 16);
}

// ---------------------------------------------------------------------------
// Prep: Wc = W_ih @ W1 (bf16), W_hh -> bf16, bc = W_ih @ b1 + b_ih (fp32).
// grid 384 (one gate row g), block 128 (one output col d).
// ---------------------------------------------------------------------------
__global__ void prep_kernel(const float* __restrict__ W1, const float* __restrict__ b1,
                            const float* __restrict__ W_ih, const float* __restrict__ W_hh,
                            const float* __restrict__ b_ih,
                            short* __restrict__ wc_bf, short* __restrict__ whh_bf,
                            float* __restrict__ bc) {
  const int g = blockIdx.x;
  const int d = threadIdx.x;
  float acc = 0.f;
  #pragma unroll 4
  for (int k = 0; k < 128; ++k)
    acc = fmaf(W_ih[g * 128 + k], W1[k * 128 + d], acc);
  wc_bf[g * 128 + d]  = f2bf(acc);
  whh_bf[g * 128 + d] = f2bf(W_hh[g * 128 + d]);

  __shared__ float red[128];
  red[d] = W_ih[g * 128 + d] * b1[d];
  __syncthreads();
  #pragma unroll
  for (int s = 64; s > 0; s >>= 1) {
    if (d < s) red[d] += red[d + s];
    __syncthreads();
  }
  if (d == 0) bc[g] = red[0] + b_ih[g];
}

// fused GRU gate math: returns h_new.
// gir/giz already include (bc + b_hh) for r,z; gin includes bc only.
__device__ __forceinline__ float gate_h(float gir, float giz, float gin,
                                        float ghr, float ghz, float ghn,
                                        float bhn, float hp) {
  const float r = __builtin_amdgcn_rcpf(1.f + __expf(-(gir + ghr)));
  const float z = __builtin_amdgcn_rcpf(1.f + __expf(-(giz + ghz)));
  float nv = gin + r * (ghn + bhn);
  nv = fminf(fmaxf(nv, -15.f), 15.f);
  const float e = __expf(2.f * nv);
  const float n = 1.f - 2.f * __builtin_amdgcn_rcpf(e + 1.f);   // tanh(nv)
  return z * (hp - n) + n;
}

// ---------------------------------------------------------------------------
// Main GRU kernel. 256 blocks (2 batch chains) x 512 threads (8 waves,
// 2 waves/SIMD for latency hiding). Wave w owns hidden slice
// j in [16w, 16w+16): three 16-wide gate-row tiles (r: j, z: 128+j, n: 256+j).
// Gate math happens IN-REGISTER on the MFMA accumulators (D rows 0,1 =
// quad0 regs 0,1) -> no gh LDS round trip, ONE barrier per step.
// h double-buffered in LDS (buffer parity = s&1, compile-time via unroll).
// Biases folded into gi at chunk-store; h_prev kept in registers.
// mfma_f32_16x16x32_bf16 layouts (m89-verified):
//   A[m=lane&15][k=quad*8+j], B[k=quad*8+j][n=lane&15], D: col=lane&15,row=quad*4+reg
// ---------------------------------------------------------------------------
__global__ __launch_bounds__(512, 2) void gru_kernel(
    const float* __restrict__ x,       // [T][B][D]
    const float* __restrict__ b_hh,    // [384]
    const short* __restrict__ wc_bf,   // [384][128] bf16
    const short* __restrict__ whh_bf,  // [384][128] bf16
    const float* __restrict__ bc,      // [384]
    float* __restrict__ out)           // [B][H]
{
  const int tid  = threadIdx.x;
  const int w    = tid >> 6;      // wave 0..7
  const int l    = tid & 63;
  const int quad = l >> 4;
  const int col  = l & 15;
  const int b0   = blockIdx.x * 2;
  const int jg   = w * 16 + col;  // this lane's gate column (0..127)

  __shared__ float gi_lds[16][385];     // [m=2*trel+chain][gate], +1 pad
  __shared__ short h_b16[2][2][128];    // [buf][chain][j]

  // ---- B-fragments for this wave's 3 gate tiles (r,z,n), all K
  bf16x8 Bc[3][4], Bh[3][4];
  #pragma unroll
  for (int g = 0; g < 3; ++g) {
    const int row = g * 128 + jg;
    #pragma unroll
    for (int kt = 0; kt < 4; ++kt) {
      const int off = row * 128 + kt * 32 + quad * 8;
      Bc[g][kt] = *(const bf16x8*)(wc_bf + off);
      Bh[g][kt] = *(const bf16x8*)(whh_bf + off);
    }
  }
  // per-lane bias folds
  const float fold_r = bc[jg]       + b_hh[jg];
  const float fold_z = bc[128 + jg] + b_hh[128 + jg];
  const float fold_n = bc[256 + jg];
  const float bhn    = b_hh[256 + jg];

  if (tid < 256) ((short*)h_b16)[tid] = 0;   // zero h buffer 0
  __syncthreads();

  float hp0 = 0.f, hp1 = 0.f;               // h_prev for chains 0,1 (quad0 lanes)

  // ---- prefetch x for chunk 0 (per-lane A-frag source: 8 f32x4)
  const int trel = col >> 1, bsel = col & 1;
  f32x4 xv[8];
  {
    const float* xb = x + ((size_t)trel * BATCH + (b0 + bsel)) * DIM + quad * 8;
    #pragma unroll
    for (int kt = 0; kt < 4; ++kt) {
      xv[2 * kt]     = *(const f32x4*)(xb + kt * 32);
      xv[2 * kt + 1] = *(const f32x4*)(xb + kt * 32 + 4);
    }
  }

  const f32x4 zero4 = {0.f, 0.f, 0.f, 0.f};

  for (int t0 = 0; t0 < T_STEPS; t0 += 8) {
    // ---- convert prefetched x to bf16 A-fragments
    bf16x8 Ax[4];
    #pragma unroll
    for (int kt = 0; kt < 4; ++kt) {
      const f32x4 v0 = xv[2 * kt], v1 = xv[2 * kt + 1];
      bf16x8 a;
      a[0] = f2bf(v0[0]); a[1] = f2bf(v0[1]); a[2] = f2bf(v0[2]); a[3] = f2bf(v0[3]);
      a[4] = f2bf(v1[0]); a[5] = f2bf(v1[1]); a[6] = f2bf(v1[2]); a[7] = f2bf(v1[3]);
      Ax[kt] = a;
    }
    // ---- prefetch next chunk (8 steps of MFMA to hide HBM latency)
    if (t0 + 8 < T_STEPS) {
      const float* xb = x + ((size_t)(t0 + 8 + trel) * BATCH + (b0 + bsel)) * DIM + quad * 8;
      #pragma unroll
      for (int kt = 0; kt < 4; ++kt) {
        xv[2 * kt]     = *(const f32x4*)(xb + kt * 32);
        xv[2 * kt + 1] = *(const f32x4*)(xb + kt * 32 + 4);
      }
    }
    // ---- gi for 8 steps x 2 chains (M=16), this wave's 3 tiles
    f32x4 gacc[3] = {zero4, zero4, zero4};
    #pragma unroll
    for (int kt = 0; kt < 4; ++kt)
      #pragma unroll
      for (int g = 0; g < 3; ++g)
        gacc[g] = __builtin_amdgcn_mfma_f32_16x16x32_bf16(Ax[kt], Bc[g][kt], gacc[g], 0, 0, 0);
    #pragma unroll
    for (int g = 0; g < 3; ++g) {
      const float fold = (g == 0) ? fold_r : ((g == 1) ? fold_z : fold_n);
      const int gc = g * 128 + jg;
      #pragma unroll
      for (int r = 0; r < 4; ++r)
        gi_lds[quad * 4 + r][gc] = gacc[g][r] + fold;
    }
    __syncthreads();

    // ---- 8 recurrent steps, fully unrolled (buffer parity compile-time)
    #pragma unroll
    for (int s = 0; s < 8; ++s) {
      const int rp = s & 1, wp = rp ^ 1;
      // h A-fragment reads (buffer rp); rows>=2 duplicate chain col&1 (unused)
      bf16x8 Ah[4];
      #pragma unroll
      for (int kt = 0; kt < 4; ++kt)
        Ah[kt] = *(const bf16x8*)(&h_b16[rp][col & 1][kt * 32 + quad * 8]);
      // gi reads for this step (issue early; consumed after MFMAs)
      const int m0 = 2 * s;
      const float gir0 = gi_lds[m0][jg],           gir1 = gi_lds[m0 + 1][jg];
      const float giz0 = gi_lds[m0][128 + jg],     giz1 = gi_lds[m0 + 1][128 + jg];
      const float gin0 = gi_lds[m0][256 + jg],     gin1 = gi_lds[m0 + 1][256 + jg];

      f32x4 acc[3] = {zero4, zero4, zero4};
      #pragma unroll
      for (int kt = 0; kt < 4; ++kt)
        #pragma unroll
        for (int g = 0; g < 3; ++g)
          acc[g] = __builtin_amdgcn_mfma_f32_16x16x32_bf16(Ah[kt], Bh[g][kt], acc[g], 0, 0, 0);

      // in-register gate math; results valid in quad0 (rows 0,1 = regs 0,1)
      const float h0 = gate_h(gir0, giz0, gin0, acc[0][0], acc[1][0], acc[2][0], bhn, hp0);
      const float h1 = gate_h(gir1, giz1, gin1, acc[0][1], acc[1][1], acc[2][1], bhn, hp1);
      hp0 = h0; hp1 = h1;
      if (quad == 0) {
        h_b16[wp][0][jg] = f2bf(h0);
        h_b16[wp][1][jg] = f2bf(h1);
      }
      __syncthreads();
    }
  }

  // ---- epilogue: final h from registers
  if (quad == 0) {
    out[(size_t)(b0 + 0) * DIM + jg] = hp0;
    out[(size_t)(b0 + 1) * DIM + jg] = hp1;
  }
}

// ---------------------------------------------------------------------------
extern "C" void kernel_launch(void* const* d_in, const int* in_sizes, int n_in,
                              void* d_out, int out_size, void* d_ws, size_t ws_size,
                              hipStream_t stream) {
  const float* x    = (const float*)d_in[0];
  const float* W1   = (const float*)d_in[1];
  const float* b1   = (const float*)d_in[2];
  const float* W_ih = (const float*)d_in[3];
  const float* W_hh = (const float*)d_in[4];
  const float* b_ih = (const float*)d_in[5];
  const float* b_hh = (const float*)d_in[6];
  float* out = (float*)d_out;

  char* ws = (char*)d_ws;
  short* wc_bf  = (short*)(ws);             // 384*128 bf16 = 98304 B
  short* whh_bf = (short*)(ws + 98304);     // 384*128 bf16 = 98304 B
  float* bc     = (float*)(ws + 196608);    // 384 fp32

  prep_kernel<<<dim3(G3), dim3(128), 0, stream>>>(W1, b1, W_ih, W_hh, b_ih, wc_bf, whh_bf, bc);
  gru_kernel<<<dim3(BATCH / 2), dim3(512), 0, stream>>>(x, b_hh, wc_bf, whh_bf, bc, out);
}

// Round 3
// 723.170 us; speedup vs baseline: 1.6042x; 1.2360x over previous
//
#include <hip/hip_runtime.h>
#include <hip/hip_bf16.h>

// Problem constants (reference: T,B,D,H = 1024,512,128,128)
#define T_STEPS 1024
#define BATCH   512
#define DIM     128
#define G3      384          // 3*H gate rows
#define NCHUNK  (T_STEPS/8)  // 128 chunks of 8 steps

typedef __attribute__((ext_vector_type(8))) short bf16x8;
typedef __attribute__((ext_vector_type(4))) float f32x4;

__device__ __forceinline__ short f2bf(float f) {
  unsigned u = __builtin_bit_cast(unsigned, f);
  u += 0x7FFFu + ((u >> 16) & 1u);   // round-to-nearest-even
  return (short)(u >> 16);
}

// LDS-only barrier: drains LDS ops for cross-wave visibility but does NOT
// drain vmcnt -> producer global prefetch stays in flight across steps.
__device__ __forceinline__ void block_sync_lds() {
  asm volatile("s_waitcnt lgkmcnt(0)\n\ts_barrier" ::: "memory");
}

// ---------------------------------------------------------------------------
// Prep: Wc = W_ih @ W1 (bf16), W_hh -> bf16, bc = W_ih @ b1 + b_ih (fp32).
// ---------------------------------------------------------------------------
__global__ void prep_kernel(const float* __restrict__ W1, const float* __restrict__ b1,
                            const float* __restrict__ W_ih, const float* __restrict__ W_hh,
                            const float* __restrict__ b_ih,
                            short* __restrict__ wc_bf, short* __restrict__ whh_bf,
                            float* __restrict__ bc) {
  const int g = blockIdx.x;
  const int d = threadIdx.x;
  float acc = 0.f;
  #pragma unroll 4
  for (int k = 0; k < 128; ++k)
    acc = fmaf(W_ih[g * 128 + k], W1[k * 128 + d], acc);
  wc_bf[g * 128 + d]  = f2bf(acc);
  whh_bf[g * 128 + d] = f2bf(W_hh[g * 128 + d]);

  __shared__ float red[128];
  red[d] = W_ih[g * 128 + d] * b1[d];
  __syncthreads();
  #pragma unroll
  for (int s = 64; s > 0; s >>= 1) {
    if (d < s) red[d] += red[d + s];
    __syncthreads();
  }
  if (d == 0) bc[g] = red[0] + b_ih[g];
}

// fused GRU gate math; gir/giz include (bc + b_hh), gin includes bc only.
__device__ __forceinline__ float gate_h(float gir, float giz, float gin,
                                        float ghr, float ghz, float ghn,
                                        float bhn, float hp) {
  const float r = __builtin_amdgcn_rcpf(1.f + __expf(-(gir + ghr)));
  const float z = __builtin_amdgcn_rcpf(1.f + __expf(-(giz + ghz)));
  float nv = gin + r * (ghn + bhn);
  nv = fminf(fmaxf(nv, -15.f), 15.f);
  const float e = __expf(2.f * nv);
  const float n = 1.f - 2.f * __builtin_amdgcn_rcpf(e + 1.f);   // tanh(nv)
  return z * (hp - n) + n;
}

// ---------------------------------------------------------------------------
// Main GRU kernel. 256 blocks (2 chains) x 512 threads (8 waves, 2/SIMD).
// Waves 0-3 = CONSUMERS: wave w owns h-cols [32w, 32w+32) (two 16-tiles x 3
// gates = 6 N-tiles); does gh MFMAs + gate math. Chain->A-row mapping:
// chain0 -> row 0 (quad0 reg0), chain1 -> row 4 (quad1 reg0), so gate math
// uses quads 0 AND 1 (1 chain x 2 cols per lane).
// Waves 4-7 = PRODUCERS: compute gi (batched 8 steps, M=16) for chunk c+1
// during chunk c's steps; double-buffered gi4; x prefetched 1 chunk ahead.
// mfma_f32_16x16x32_bf16 layouts (m89-verified):
//   A[m=lane&15][k=quad*8+j], B[k=quad*8+j][n=lane&15], D: col=lane&15,row=quad*4+reg
// ---------------------------------------------------------------------------
__global__ __launch_bounds__(512, 2) void gru_kernel(
    const float* __restrict__ x,       // [T][B][D]
    const float* __restrict__ b_hh,    // [384]
    const short* __restrict__ wc_bf,   // [384][128] bf16
    const short* __restrict__ whh_bf,  // [384][128] bf16
    const float* __restrict__ bc,      // [384]
    float* __restrict__ out)           // [B][H]
{
  const int tid = threadIdx.x;
  const int w   = tid >> 6;       // wave 0..7
  const int l   = tid & 63;
  const int q   = l >> 4;         // quad
  const int c   = l & 15;         // col-in-tile / A-row
  const int b0  = blockIdx.x * 2;

  __shared__ f32x4 gi4[2][16][128];   // [buf][m=2*step+chain][gatecol] (r,z,n,_) 64 KB
  __shared__ short hbuf[2][2][128];   // [parity][chain][j] bf16

  const f32x4 zero4 = {0.f, 0.f, 0.f, 0.f};

  if (w < 4) {
    // ================= CONSUMER =================
    const int jg0 = w * 32 + c, jg1 = jg0 + 16;
    bf16x8 Bh[3][2][4];
    #pragma unroll
    for (int g = 0; g < 3; ++g)
      #pragma unroll
      for (int Tt = 0; Tt < 2; ++Tt)
        #pragma unroll
        for (int kt = 0; kt < 4; ++kt)
          Bh[g][Tt][kt] = *(const bf16x8*)(whh_bf +
              (g * 128 + w * 32 + Tt * 16 + c) * 128 + kt * 32 + q * 8);
    const float bhn0 = b_hh[256 + jg0], bhn1 = b_hh[256 + jg1];

    ((short*)hbuf)[tid] = 0;          // tids 0..255 zero hbuf[0] exactly
    float hpA = 0.f, hpB = 0.f;       // h_prev: chain q, cols jg0/jg1 (valid q<2)
    __syncthreads();

    const int ch = (c >> 2) & 1;      // A-row c -> chain (rows 0-3:0, 4-7:1, dup after)
    const short* hbase0 = &hbuf[0][ch][q * 8];
    const short* hbase1 = &hbuf[1][ch][q * 8];
    const int mrow = q & 1;           // gi row parity for this quad's chain

    for (int cc = 0; cc < NCHUNK; ++cc) {
      const f32x4* gp = &gi4[cc & 1][mrow][0];
      #pragma unroll
      for (int s = 0; s < 8; ++s) {
        const short* hb = (s & 1) ? hbase1 : hbase0;
        bf16x8 Ah[4];
        #pragma unroll
        for (int kt = 0; kt < 4; ++kt)
          Ah[kt] = *(const bf16x8*)(hb + kt * 32);
        const f32x4 giA = gp[2 * s * 128 + jg0];
        const f32x4 giB = gp[2 * s * 128 + jg1];

        f32x4 a0[3] = {zero4, zero4, zero4};
        f32x4 a1[3] = {zero4, zero4, zero4};
        #pragma unroll
        for (int kt = 0; kt < 4; ++kt)
          #pragma unroll
          for (int g = 0; g < 3; ++g) {
            a0[g] = __builtin_amdgcn_mfma_f32_16x16x32_bf16(Ah[kt], Bh[g][0][kt], a0[g], 0, 0, 0);
            a1[g] = __builtin_amdgcn_mfma_f32_16x16x32_bf16(Ah[kt], Bh[g][1][kt], a1[g], 0, 0, 0);
          }
        // reg0 = D-row 4q: q0 -> chain0, q1 -> chain1; q>=2 garbage (unused)
        const float hA = gate_h(giA[0], giA[1], giA[2], a0[0][0], a0[1][0], a0[2][0], bhn0, hpA);
        const float hB = gate_h(giB[0], giB[1], giB[2], a1[0][0], a1[1][0], a1[2][0], bhn1, hpB);
        hpA = hA; hpB = hB;
        if (q < 2) {
          const int wp = (s & 1) ^ 1;
          hbuf[wp][q][jg0] = f2bf(hA);
          hbuf[wp][q][jg1] = f2bf(hB);
        }
        block_sync_lds();
      }
    }
    if (q < 2) {
      out[(size_t)(b0 + q) * DIM + jg0] = hpA;
      out[(size_t)(b0 + q) * DIM + jg1] = hpB;
    }
  } else {
    // ================= PRODUCER =================
    const int w4 = w - 4;
    const int jg0 = w4 * 32 + c, jg1 = jg0 + 16;
    bf16x8 Bc[3][2][4];
    #pragma unroll
    for (int g = 0; g < 3; ++g)
      #pragma unroll
      for (int Tt = 0; Tt < 2; ++Tt)
        #pragma unroll
        for (int kt = 0; kt < 4; ++kt)
          Bc[g][Tt][kt] = *(const bf16x8*)(wc_bf +
              (g * 128 + w4 * 32 + Tt * 16 + c) * 128 + kt * 32 + q * 8);
    const float fr0 = bc[jg0]       + b_hh[jg0];
    const float fz0 = bc[128 + jg0] + b_hh[128 + jg0];
    const float fn0 = bc[256 + jg0];
    const float fr1 = bc[jg1]       + b_hh[jg1];
    const float fz1 = bc[128 + jg1] + b_hh[128 + jg1];
    const float fn1 = bc[256 + jg1];

    const int trel = c >> 1, chn = c & 1;   // A-row m = c = 2*trel + chn
    const size_t xstride = (size_t)BATCH * DIM;
    f32x4 xv[8];

    // ---- pre-phase: build chunk 0 into buf 0, then prefetch chunk 1
    {
      const float* xb = x + ((size_t)trel * BATCH + (b0 + chn)) * DIM + q * 8;
      f32x4 xt[8];
      #pragma unroll
      for (int kt = 0; kt < 4; ++kt) {
        xt[2 * kt]     = *(const f32x4*)(xb + kt * 32);
        xt[2 * kt + 1] = *(const f32x4*)(xb + kt * 32 + 4);
      }
      bf16x8 Ax[4];
      #pragma unroll
      for (int kt = 0; kt < 4; ++kt) {
        const f32x4 v0 = xt[2 * kt], v1 = xt[2 * kt + 1];
        bf16x8 a;
        a[0] = f2bf(v0[0]); a[1] = f2bf(v0[1]); a[2] = f2bf(v0[2]); a[3] = f2bf(v0[3]);
        a[4] = f2bf(v1[0]); a[5] = f2bf(v1[1]); a[6] = f2bf(v1[2]); a[7] = f2bf(v1[3]);
        Ax[kt] = a;
      }
      f32x4 ga[2][3] = {{zero4, zero4, zero4}, {zero4, zero4, zero4}};
      #pragma unroll
      for (int kt = 0; kt < 4; ++kt)
        #pragma unroll
        for (int g = 0; g < 3; ++g) {
          ga[0][g] = __builtin_amdgcn_mfma_f32_16x16x32_bf16(Ax[kt], Bc[g][0][kt], ga[0][g], 0, 0, 0);
          ga[1][g] = __builtin_amdgcn_mfma_f32_16x16x32_bf16(Ax[kt], Bc[g][1][kt], ga[1][g], 0, 0, 0);
        }
      #pragma unroll
      for (int r = 0; r < 4; ++r) {
        f32x4 vA = {ga[0][0][r] + fr0, ga[0][1][r] + fz0, ga[0][2][r] + fn0, 0.f};
        f32x4 vB = {ga[1][0][r] + fr1, ga[1][1][r] + fz1, ga[1][2][r] + fn1, 0.f};
        gi4[0][4 * q + r][jg0] = vA;
        gi4[0][4 * q + r][jg1] = vB;
      }
      // prefetch chunk 1
      const float* xb1 = x + ((size_t)(8 + trel) * BATCH + (b0 + chn)) * DIM + q * 8;
      #pragma unroll
      for (int kt = 0; kt < 4; ++kt) {
        xv[2 * kt]     = *(const f32x4*)(xb1 + kt * 32);
        xv[2 * kt + 1] = *(const f32x4*)(xb1 + kt * 32 + 4);
      }
    }
    __syncthreads();

    for (int cc = 0; cc < NCHUNK; ++cc) {
      const int tc = cc + 1;            // chunk being produced
      bf16x8 Ax[4];
      f32x4 ga[2][3];
      #pragma unroll
      for (int s = 0; s < 8; ++s) {
        if (tc < NCHUNK) {
          if (s == 0) {
            #pragma unroll
            for (int kt = 0; kt < 4; ++kt) {
              const f32x4 v0 = xv[2 * kt], v1 = xv[2 * kt + 1];
              bf16x8 a;
              a[0] = f2bf(v0[0]); a[1] = f2bf(v0[1]); a[2] = f2bf(v0[2]); a[3] = f2bf(v0[3]);
              a[4] = f2bf(v1[0]); a[5] = f2bf(v1[1]); a[6] = f2bf(v1[2]); a[7] = f2bf(v1[3]);
              Ax[kt] = a;
            }
            #pragma unroll
            for (int Tt = 0; Tt < 2; ++Tt)
              #pragma unroll
              for (int g = 0; g < 3; ++g) ga[Tt][g] = zero4;
          } else if (s <= 4) {
            const int kt = s - 1;
            #pragma unroll
            for (int g = 0; g < 3; ++g) {
              ga[0][g] = __builtin_amdgcn_mfma_f32_16x16x32_bf16(Ax[kt], Bc[g][0][kt], ga[0][g], 0, 0, 0);
              ga[1][g] = __builtin_amdgcn_mfma_f32_16x16x32_bf16(Ax[kt], Bc[g][1][kt], ga[1][g], 0, 0, 0);
            }
          } else if (s == 5) {
            if (tc + 1 < NCHUNK) {   // prefetch chunk tc+1 (in flight across barriers)
              const float* xb = x + ((size_t)(tc + 1) * 8 * xstride / xstride * 0 +
                                     ((size_t)((tc + 1) * 8 + trel) * BATCH + (b0 + chn)) * DIM) + q * 8;
              #pragma unroll
              for (int kt = 0; kt < 4; ++kt) {
                xv[2 * kt]     = *(const f32x4*)(xb + kt * 32);
                xv[2 * kt + 1] = *(const f32x4*)(xb + kt * 32 + 4);
              }
            }
          } else if (s == 6) {
            #pragma unroll
            for (int r = 0; r < 4; ++r) {
              ga[0][0][r] += fr0; ga[0][1][r] += fz0; ga[0][2][r] += fn0;
              ga[1][0][r] += fr1; ga[1][1][r] += fz1; ga[1][2][r] += fn1;
            }
          } else {  // s == 7: write gi for chunk tc
            const int nbuf = tc & 1;
            #pragma unroll
            for (int r = 0; r < 4; ++r) {
              f32x4 vA = {ga[0][0][r], ga[0][1][r], ga[0][2][r], 0.f};
              f32x4 vB = {ga[1][0][r], ga[1][1][r], ga[1][2][r], 0.f};
              gi4[nbuf][4 * q + r][jg0] = vA;
              gi4[nbuf][4 * q + r][jg1] = vB;
            }
          }
        }
        block_sync_lds();
      }
    }
  }
}

// ---------------------------------------------------------------------------
extern "C" void kernel_launch(void* const* d_in, const int* in_sizes, int n_in,
                              void* d_out, int out_size, void* d_ws, size_t ws_size,
                              hipStream_t stream) {
  const float* x    = (const float*)d_in[0];
  const float* W1   = (const float*)d_in[1];
  const float* b1   = (const float*)d_in[2];
  const float* W_ih = (const float*)d_in[3];
  const float* W_hh = (const float*)d_in[4];
  const float* b_ih = (const float*)d_in[5];
  const float* b_hh = (const float*)d_in[6];
  float* out = (float*)d_out;

  char* ws = (char*)d_ws;
  short* wc_bf  = (short*)(ws);             // 384*128 bf16
  short* whh_bf = (short*)(ws + 98304);     // 384*128 bf16
  float* bc     = (float*)(ws + 196608);    // 384 fp32

  prep_kernel<<<dim3(G3), dim3(128), 0, stream>>>(W1, b1, W_ih, W_hh, b_ih, wc_bf, whh_bf, bc);
  gru_kernel<<<dim3(BATCH / 2), dim3(512), 0, stream>>>(x, b_hh, wc_bf, whh_bf, bc, out);
}

// Round 4
// 689.262 us; speedup vs baseline: 1.6831x; 1.0492x over previous
//
#include <hip/hip_runtime.h>
#include <hip/hip_bf16.h>

// Problem constants (reference: T,B,D,H = 1024,512,128,128)
#define T_STEPS 1024
#define BATCH   512
#define DIM     128
#define G3      384          // 3*H gate rows
#define NCHUNK  (T_STEPS/8)  // 128 chunks of 8 steps

typedef __attribute__((ext_vector_type(8))) short bf16x8;
typedef __attribute__((ext_vector_type(4))) float f32x4;

__device__ __forceinline__ short f2bf(float f) {
  unsigned u = __builtin_bit_cast(unsigned, f);
  u += 0x7FFFu + ((u >> 16) & 1u);   // round-to-nearest-even
  return (short)(u >> 16);
}

// LDS-only barrier: drains LDS ops for cross-wave visibility but does NOT
// drain vmcnt -> producer global prefetch stays in flight across steps.
__device__ __forceinline__ void block_sync_lds() {
  asm volatile("s_waitcnt lgkmcnt(0)\n\ts_barrier" ::: "memory");
}

// ---------------------------------------------------------------------------
// Prep: Wc = W_ih @ W1 (bf16), W_hh -> bf16, bc = W_ih @ b1 + b_ih (fp32).
// ---------------------------------------------------------------------------
__global__ void prep_kernel(const float* __restrict__ W1, const float* __restrict__ b1,
                            const float* __restrict__ W_ih, const float* __restrict__ W_hh,
                            const float* __restrict__ b_ih,
                            short* __restrict__ wc_bf, short* __restrict__ whh_bf,
                            float* __restrict__ bc) {
  const int g = blockIdx.x;
  const int d = threadIdx.x;
  float acc = 0.f;
  #pragma unroll 4
  for (int k = 0; k < 128; ++k)
    acc = fmaf(W_ih[g * 128 + k], W1[k * 128 + d], acc);
  wc_bf[g * 128 + d]  = f2bf(acc);
  whh_bf[g * 128 + d] = f2bf(W_hh[g * 128 + d]);

  __shared__ float red[128];
  red[d] = W_ih[g * 128 + d] * b1[d];
  __syncthreads();
  #pragma unroll
  for (int s = 64; s > 0; s >>= 1) {
    if (d < s) red[d] += red[d + s];
    __syncthreads();
  }
  if (d == 0) bc[g] = red[0] + b_ih[g];
}

// fused GRU gate math; gir/giz include (bc + b_hh), gin includes bc only.
__device__ __forceinline__ float gate_h(float gir, float giz, float gin,
                                        float ghr, float ghz, float ghn,
                                        float bhn, float hp) {
  const float r = __builtin_amdgcn_rcpf(1.f + __expf(-(gir + ghr)));
  const float z = __builtin_amdgcn_rcpf(1.f + __expf(-(giz + ghz)));
  float nv = gin + r * (ghn + bhn);
  nv = fminf(fmaxf(nv, -15.f), 15.f);
  const float e = __expf(2.f * nv);
  const float n = 1.f - 2.f * __builtin_amdgcn_rcpf(e + 1.f);   // tanh(nv)
  return z * (hp - n) + n;
}

// ---------------------------------------------------------------------------
// Main GRU kernel. 256 blocks (2 chains) x 512 threads (8 waves, 2/SIMD).
// Waves 0-3 = CONSUMERS. Wave w owns h-cols [32w, 32w+32) = two 16-tiles x 3
// gates = 6 N-tiles = 24 MFMA/step. DUPLICATE-ROW A-frag: A rows 0-7 carry
// h[chain0], rows 8-15 h[chain1] (lane reads hbuf[c>>3]). D reg0 of quads
// {0,1,2,3} then holds {ch0,ch0,ch1,ch1} results, so quad parity selects the
// column half and EVERY lane does exactly one gate_h:
//   lane(q,c): chain = q>>1, col = 32w + 16*(q&1) + c, gh from (q&1 ? a1 : a0).
// gi prefetched to registers for the whole 8-step chunk (8 x b128 / lane).
// Waves 4-7 = PRODUCERS: gi for chunk c+1 during chunk c (M=16 = 8 steps x
// 2 chains), double-buffered gi4; x prefetched one chunk ahead; biases folded.
// mfma_f32_16x16x32_bf16 layouts (m89-verified):
//   A[m=lane&15][k=quad*8+j], B[k=quad*8+j][n=lane&15], D: col=lane&15,row=quad*4+reg
// ---------------------------------------------------------------------------
__global__ __launch_bounds__(512, 2) void gru_kernel(
    const float* __restrict__ x,       // [T][B][D]
    const float* __restrict__ b_hh,    // [384]
    const short* __restrict__ wc_bf,   // [384][128] bf16
    const short* __restrict__ whh_bf,  // [384][128] bf16
    const float* __restrict__ bc,      // [384]
    float* __restrict__ out)           // [B][H]
{
  const int tid = threadIdx.x;
  const int w   = tid >> 6;       // wave 0..7
  const int l   = tid & 63;
  const int q   = l >> 4;         // quad
  const int c   = l & 15;         // col-in-tile / A-row
  const int b0  = blockIdx.x * 2;

  __shared__ f32x4 gi4[2][16][128];   // [buf][m=2*step+chain][gatecol] (r,z,n,_) 64 KB
  __shared__ short hbuf[2][2][128];   // [parity][chain][j] bf16

  const f32x4 zero4 = {0.f, 0.f, 0.f, 0.f};

  if (w < 4) {
    // ================= CONSUMER =================
    const int half = q & 1;                    // 0 -> a0 cols, 1 -> a1 cols
    const int ch   = q >> 1;                   // this lane's chain
    const int colX = w * 32 + (half << 4) + c; // this lane's hidden col

    bf16x8 Bh[3][2][4];
    #pragma unroll
    for (int g = 0; g < 3; ++g)
      #pragma unroll
      for (int Tt = 0; Tt < 2; ++Tt)
        #pragma unroll
        for (int kt = 0; kt < 4; ++kt)
          Bh[g][Tt][kt] = *(const bf16x8*)(whh_bf +
              (g * 128 + w * 32 + Tt * 16 + c) * 128 + kt * 32 + q * 8);
    const float bhn = b_hh[256 + colX];

    ((short*)hbuf)[tid] = 0;        // tids 0..255 zero hbuf[0][*][*] exactly
    float hp = 0.f;
    __syncthreads();

    // A-row c -> chain c>>3 (rows 0-7: chain0, 8-15: chain1), broadcast reads
    const short* hb0 = &hbuf[0][c >> 3][q * 8];
    const short* hb1 = &hbuf[1][c >> 3][q * 8];

    for (int cc = 0; cc < NCHUNK; ++cc) {
      // chunk-level gi prefetch: one b128 per step for this lane
      f32x4 gi[8];
      {
        const f32x4* gp = &gi4[cc & 1][ch][colX];
        #pragma unroll
        for (int s = 0; s < 8; ++s) gi[s] = gp[2 * s * 128];
      }
      #pragma unroll
      for (int s = 0; s < 8; ++s) {
        const short* hb = (s & 1) ? hb1 : hb0;
        bf16x8 Ah[4];
        #pragma unroll
        for (int kt = 0; kt < 4; ++kt)
          Ah[kt] = *(const bf16x8*)(hb + kt * 32);

        f32x4 a0[3] = {zero4, zero4, zero4};
        f32x4 a1[3] = {zero4, zero4, zero4};
        #pragma unroll
        for (int kt = 0; kt < 4; ++kt)
          #pragma unroll
          for (int g = 0; g < 3; ++g) {
            a0[g] = __builtin_amdgcn_mfma_f32_16x16x32_bf16(Ah[kt], Bh[g][0][kt], a0[g], 0, 0, 0);
            a1[g] = __builtin_amdgcn_mfma_f32_16x16x32_bf16(Ah[kt], Bh[g][1][kt], a1[g], 0, 0, 0);
          }
        // quad parity picks the column-half accumulator; reg0 = this quad's chain row
        const float ghr = half ? a1[0][0] : a0[0][0];
        const float ghz = half ? a1[1][0] : a0[1][0];
        const float ghn = half ? a1[2][0] : a0[2][0];
        const float h = gate_h(gi[s][0], gi[s][1], gi[s][2], ghr, ghz, ghn, bhn, hp);
        hp = h;
        hbuf[(s & 1) ^ 1][ch][colX] = f2bf(h);
        block_sync_lds();
      }
    }
    out[(size_t)(b0 + ch) * DIM + colX] = hp;
  } else {
    // ================= PRODUCER =================
    const int w4 = w - 4;
    const int jg0 = w4 * 32 + c, jg1 = jg0 + 16;
    bf16x8 Bc[3][2][4];
    #pragma unroll
    for (int g = 0; g < 3; ++g)
      #pragma unroll
      for (int Tt = 0; Tt < 2; ++Tt)
        #pragma unroll
        for (int kt = 0; kt < 4; ++kt)
          Bc[g][Tt][kt] = *(const bf16x8*)(wc_bf +
              (g * 128 + w4 * 32 + Tt * 16 + c) * 128 + kt * 32 + q * 8);
    const float fr0 = bc[jg0]       + b_hh[jg0];
    const float fz0 = bc[128 + jg0] + b_hh[128 + jg0];
    const float fn0 = bc[256 + jg0];
    const float fr1 = bc[jg1]       + b_hh[jg1];
    const float fz1 = bc[128 + jg1] + b_hh[128 + jg1];
    const float fn1 = bc[256 + jg1];

    const int trel = c >> 1, chn = c & 1;   // A-row m = c = 2*trel + chn
    f32x4 xv[8];

    // ---- pre-phase: build chunk 0 into buf 0, then prefetch chunk 1
    {
      const float* xb = x + ((size_t)trel * BATCH + (b0 + chn)) * DIM + q * 8;
      f32x4 xt[8];
      #pragma unroll
      for (int kt = 0; kt < 4; ++kt) {
        xt[2 * kt]     = *(const f32x4*)(xb + kt * 32);
        xt[2 * kt + 1] = *(const f32x4*)(xb + kt * 32 + 4);
      }
      bf16x8 Ax[4];
      #pragma unroll
      for (int kt = 0; kt < 4; ++kt) {
        const f32x4 v0 = xt[2 * kt], v1 = xt[2 * kt + 1];
        bf16x8 a;
        a[0] = f2bf(v0[0]); a[1] = f2bf(v0[1]); a[2] = f2bf(v0[2]); a[3] = f2bf(v0[3]);
        a[4] = f2bf(v1[0]); a[5] = f2bf(v1[1]); a[6] = f2bf(v1[2]); a[7] = f2bf(v1[3]);
        Ax[kt] = a;
      }
      f32x4 ga[2][3] = {{zero4, zero4, zero4}, {zero4, zero4, zero4}};
      #pragma unroll
      for (int kt = 0; kt < 4; ++kt)
        #pragma unroll
        for (int g = 0; g < 3; ++g) {
          ga[0][g] = __builtin_amdgcn_mfma_f32_16x16x32_bf16(Ax[kt], Bc[g][0][kt], ga[0][g], 0, 0, 0);
          ga[1][g] = __builtin_amdgcn_mfma_f32_16x16x32_bf16(Ax[kt], Bc[g][1][kt], ga[1][g], 0, 0, 0);
        }
      #pragma unroll
      for (int r = 0; r < 4; ++r) {
        f32x4 vA = {ga[0][0][r] + fr0, ga[0][1][r] + fz0, ga[0][2][r] + fn0, 0.f};
        f32x4 vB = {ga[1][0][r] + fr1, ga[1][1][r] + fz1, ga[1][2][r] + fn1, 0.f};
        gi4[0][4 * q + r][jg0] = vA;
        gi4[0][4 * q + r][jg1] = vB;
      }
      const float* xb1 = x + ((size_t)(8 + trel) * BATCH + (b0 + chn)) * DIM + q * 8;
      #pragma unroll
      for (int kt = 0; kt < 4; ++kt) {
        xv[2 * kt]     = *(const f32x4*)(xb1 + kt * 32);
        xv[2 * kt + 1] = *(const f32x4*)(xb1 + kt * 32 + 4);
      }
    }
    __syncthreads();

    for (int cc = 0; cc < NCHUNK; ++cc) {
      const int tc = cc + 1;            // chunk being produced
      bf16x8 Ax[4];
      f32x4 ga[2][3];
      #pragma unroll
      for (int s = 0; s < 8; ++s) {
        if (tc < NCHUNK) {
          if (s == 0) {
            #pragma unroll
            for (int kt = 0; kt < 4; ++kt) {
              const f32x4 v0 = xv[2 * kt], v1 = xv[2 * kt + 1];
              bf16x8 a;
              a[0] = f2bf(v0[0]); a[1] = f2bf(v0[1]); a[2] = f2bf(v0[2]); a[3] = f2bf(v0[3]);
              a[4] = f2bf(v1[0]); a[5] = f2bf(v1[1]); a[6] = f2bf(v1[2]); a[7] = f2bf(v1[3]);
              Ax[kt] = a;
            }
            #pragma unroll
            for (int Tt = 0; Tt < 2; ++Tt)
              #pragma unroll
              for (int g = 0; g < 3; ++g) ga[Tt][g] = zero4;
          } else if (s <= 4) {
            const int kt = s - 1;
            #pragma unroll
            for (int g = 0; g < 3; ++g) {
              ga[0][g] = __builtin_amdgcn_mfma_f32_16x16x32_bf16(Ax[kt], Bc[g][0][kt], ga[0][g], 0, 0, 0);
              ga[1][g] = __builtin_amdgcn_mfma_f32_16x16x32_bf16(Ax[kt], Bc[g][1][kt], ga[1][g], 0, 0, 0);
            }
          } else if (s == 5) {
            if (tc + 1 < NCHUNK) {   // prefetch x for chunk tc+1 (stays in flight)
              const float* xb = x + ((size_t)((tc + 1) * 8 + trel) * BATCH + (b0 + chn)) * DIM + q * 8;
              #pragma unroll
              for (int kt = 0; kt < 4; ++kt) {
                xv[2 * kt]     = *(const f32x4*)(xb + kt * 32);
                xv[2 * kt + 1] = *(const f32x4*)(xb + kt * 32 + 4);
              }
            }
          } else if (s == 6) {
            #pragma unroll
            for (int r = 0; r < 4; ++r) {
              ga[0][0][r] += fr0; ga[0][1][r] += fz0; ga[0][2][r] += fn0;
              ga[1][0][r] += fr1; ga[1][1][r] += fz1; ga[1][2][r] += fn1;
            }
          } else {  // s == 7: publish gi for chunk tc
            const int nbuf = tc & 1;
            #pragma unroll
            for (int r = 0; r < 4; ++r) {
              f32x4 vA = {ga[0][0][r], ga[0][1][r], ga[0][2][r], 0.f};
              f32x4 vB = {ga[1][0][r], ga[1][1][r], ga[1][2][r], 0.f};
              gi4[nbuf][4 * q + r][jg0] = vA;
              gi4[nbuf][4 * q + r][jg1] = vB;
            }
          }
        }
        block_sync_lds();
      }
    }
  }
}

// ---------------------------------------------------------------------------
extern "C" void kernel_launch(void* const* d_in, const int* in_sizes, int n_in,
                              void* d_out, int out_size, void* d_ws, size_t ws_size,
                              hipStream_t stream) {
  const float* x    = (const float*)d_in[0];
  const float* W1   = (const float*)d_in[1];
  const float* b1   = (const float*)d_in[2];
  const float* W_ih = (const float*)d_in[3];
  const float* W_hh = (const float*)d_in[4];
  const float* b_ih = (const float*)d_in[5];
  const float* b_hh = (const float*)d_in[6];
  float* out = (float*)d_out;

  char* ws = (char*)d_ws;
  short* wc_bf  = (short*)(ws);             // 384*128 bf16
  short* whh_bf = (short*)(ws + 98304);     // 384*128 bf16
  float* bc     = (float*)(ws + 196608);    // 384 fp32

  prep_kernel<<<dim3(G3), dim3(128), 0, stream>>>(W1, b1, W_ih, W_hh, b_ih, wc_bf, whh_bf, bc);
  gru_kernel<<<dim3(BATCH / 2), dim3(512), 0, stream>>>(x, b_hh, wc_bf, whh_bf, bc, out);
}